// Round 15
// baseline (252.692 us; speedup 1.0000x reference)
//
#include <hip/hip_runtime.h>
#include <hip/hip_bf16.h>

// ---------------------------------------------------------------------------
// NeRF fused MLP, bf16 MFMA (16x16x32), fp32 accum, swapped operands (C^T).
// R15 = R14 + 3 blocks/CU: in-place h[64][256] (2 barriers/layer, R8-proven)
// -> LDS 48KB; __launch_bounds__(256,3) -> 84 AGPR / 84 VGPR split.
// acc[4][4] = 64 AGPR fits; CH=2 b-staging keeps VGPR side under 84.
// Deep (row&31) swizzle; fragment-order weights (coalesced 1KB b-loads);
// b64 epilogue. Occupancy 8 -> 12 waves/CU is the single variable vs R14.
// ---------------------------------------------------------------------------

typedef __bf16 bfrag __attribute__((ext_vector_type(8)));   // 8 bf16 = 4 VGPR
typedef float  f4    __attribute__((ext_vector_type(4)));   // C/D frag
typedef unsigned short us4 __attribute__((ext_vector_type(4))); // 8B LDS store

// ws layout (bf16 element offsets). Each layer: ncts*nks*512 elems,
// fragment order: elem((ks*ncts + ct)*512 + lane*8 + j) =
//   W[k = ks*32 + (lane>>4)*8 + j][col = ct*16 + (lane&15)]
constexpr int OFF_W0 = 0;        // ncts16 nks2
constexpr int OFF_W1 = 16384;    // ncts16 nks8
constexpr int OFF_W2 = 81920;
constexpr int OFF_W3 = 147456;
constexpr int OFF_W4 = 212992;
constexpr int OFF_W5 = 278528;   // ncts16 nks10 (skip: k63 = 0 pad, k>=64 -> h)
constexpr int OFF_W6 = 360448;
constexpr int OFF_W7 = 425984;
constexpr int OFF_WF = 491520;   // ncts16 nks8
constexpr int OFF_WV = 557056;   // ncts8 nks10 ([feature|views], k319 pad)
constexpr int OFF_WA = 598016;   // ncts1 nks8 (col 0 = Wa, rest 0)
constexpr int OFF_WR = 602112;   // ncts1 nks4 (cols 0..2 = Wr, rest 0)
constexpr int WS_TOTAL = 604160; // bf16 elems (~1.2 MB)

__device__ __forceinline__ unsigned swz256(int row, int k) {
  // XOR element bits 3..7 with row&31 -> 16-row fragment reads hit 16
  // distinct 16B chunks (2-way = free per m136).
  return (unsigned)((row * 256 + k) ^ ((row & 31) << 3));
}
__device__ __forceinline__ unsigned swz64(int row, int k) {
  return (unsigned)((row * 64 + k) ^ ((row & 7) << 3));
}

// MFMA phase: 4 row-tiles (64 rows) x NCT col-tiles, K = NKS*32.
// src = LDS activations (stride SSTR, swizzled) -> B operand (swapped).
// Weights (fragment order) -> A operand. acc holds C^T: lane l15 = h-row,
// (lane>>4)*4+j = 4 consecutive output cols. CH=2 b-staging (VGPR cap 84).
template<int NCT, int NKS, int NCTS, int SSTR>
__device__ __forceinline__ void phase(f4 (&acc)[4][NCT],
    const unsigned short* __restrict__ src,
    const unsigned short* __restrict__ wt, int ks0, int ctb,
    int lane, int l15, int lk8) {
#pragma unroll
  for (int ks = 0; ks < NKS; ++ks) {
    const int kl = ks * 32 + lk8;
    bfrag a[4];
#pragma unroll
    for (int rt = 0; rt < 4; ++rt) {
      const int row = rt * 16 + l15;
      const unsigned idx = (SSTR == 256) ? swz256(row, kl) : swz64(row, kl);
      a[rt] = *(const bfrag*)(src + idx);
    }
    const unsigned short* wk =
        wt + ((size_t)(ks0 + ks) * NCTS + ctb) * 512 + lane * 8;
    constexpr int CH = (NCT < 2) ? NCT : 2;
#pragma unroll
    for (int c2 = 0; c2 < NCT; c2 += CH) {
      bfrag b[CH];
#pragma unroll
      for (int u = 0; u < CH; ++u)
        b[u] = *(const bfrag*)(wk + (size_t)(c2 + u) * 512);
#pragma unroll
      for (int u = 0; u < CH; ++u)
#pragma unroll
        for (int rt = 0; rt < 4; ++rt)
          acc[rt][c2 + u] = __builtin_amdgcn_mfma_f32_16x16x32_bf16(b[u], a[rt], acc[rt][c2 + u], 0, 0, 0);
    }
  }
}

// bias init: lane covers cols cb + ct*16 + lk4 + (0..3) -> float4 load
template<int NCT>
__device__ __forceinline__ void init_acc(f4 (&acc)[4][NCT],
    const float* __restrict__ bias, int cb, int lk4) {
#pragma unroll
  for (int ct = 0; ct < NCT; ++ct) {
    const float4 bv = *(const float4*)(bias + cb + ct * 16 + lk4);
    f4 v = {bv.x, bv.y, bv.z, bv.w};
#pragma unroll
    for (int rt = 0; rt < 4; ++rt) acc[rt][ct] = v;
  }
}

// epilogue: lane writes h[row = rt*16+l15][cb + ct*16 + lk4 .. +3] as one b64
template<bool RELU, int NCT>
__device__ __forceinline__ void store_h(f4 (&acc)[4][NCT],
    unsigned short* __restrict__ h, int cb, int l15, int lk4) {
#pragma unroll
  for (int ct = 0; ct < NCT; ++ct) {
    const int col0 = cb + ct * 16 + lk4;
#pragma unroll
    for (int rt = 0; rt < 4; ++rt) {
      us4 packed;
#pragma unroll
      for (int j = 0; j < 4; ++j) {
        float v = acc[rt][ct][j];
        if (RELU) v = fmaxf(v, 0.f);
        __bf16 bb = (__bf16)v;
        packed[j] = __builtin_bit_cast(unsigned short, bb);
      }
      *(us4*)(h + swz256(rt * 16 + l15, col0)) = packed;
    }
  }
}

// stage x -> pts[64][64] (cols 0..62, pad 63) and views[64][64] (x cols 63..125)
__device__ __forceinline__ void stage_inputs(const float* __restrict__ x,
    unsigned short* pts, unsigned short* views, int rowg0, int tid) {
  const int row = tid >> 2, seg = tid & 3;
  const float* xr = x + (size_t)(rowg0 + row) * 126;
  bfrag v0, v1;
#pragma unroll
  for (int q = 0; q < 4; ++q) {          // pts, float2 (8B-aligned: even offs)
    const int c = seg * 16 + 2 * q;
    float2 t = *(const float2*)(xr + c);
    v0[2 * q]     = (c     < 63) ? (__bf16)t.x : (__bf16)0.f;
    v0[2 * q + 1] = (c + 1 < 63) ? (__bf16)t.y : (__bf16)0.f;
  }
#pragma unroll
  for (int q = 0; q < 4; ++q) {
    const int c = seg * 16 + 8 + 2 * q;
    float2 t = *(const float2*)(xr + c);   // max c=62 -> reads x[63], in-bounds
    v1[2 * q]     = (c     < 63) ? (__bf16)t.x : (__bf16)0.f;
    v1[2 * q + 1] = (c + 1 < 63) ? (__bf16)t.y : (__bf16)0.f;
  }
  *(bfrag*)(pts + swz64(row, seg * 16))     = v0;
  *(bfrag*)(pts + swz64(row, seg * 16 + 8)) = v1;
  bfrag w0, w1;
#pragma unroll
  for (int j = 0; j < 8; ++j) {          // views, scalar guarded (odd base)
    const int c = seg * 16 + j;
    w0[j] = (c < 63) ? (__bf16)xr[63 + c] : (__bf16)0.f;
  }
#pragma unroll
  for (int j = 0; j < 8; ++j) {
    const int c = seg * 16 + 8 + j;
    w1[j] = (c < 63) ? (__bf16)xr[63 + c] : (__bf16)0.f;
  }
  *(bfrag*)(views + swz64(row, seg * 16))     = w0;
  *(bfrag*)(views + swz64(row, seg * 16 + 8)) = w1;
}

// ---------------------------------------------------------------------------
struct RepackArgs {
  const float *W0, *W1, *W2, *W3, *W4, *W5, *W6, *W7, *Wf, *Wv, *Wa, *Wr;
  unsigned short* ws;
};

__global__ void repack_kernel(RepackArgs a) {
  const int i = blockIdx.x * 256 + threadIdx.x;
  if (i >= WS_TOTAL) return;

  const float* src; int off, ncts, fanin, fanout; bool shift = false;
  int mode = 0;  // 0 = dense, 1 = WA (col0 only), 2 = WR (cols 0..2)
  if      (i < OFF_W1) { src = a.W0; off = OFF_W0; ncts = 16; fanin = 63;  fanout = 256; }
  else if (i < OFF_W2) { src = a.W1; off = OFF_W1; ncts = 16; fanin = 256; fanout = 256; }
  else if (i < OFF_W3) { src = a.W2; off = OFF_W2; ncts = 16; fanin = 256; fanout = 256; }
  else if (i < OFF_W4) { src = a.W3; off = OFF_W3; ncts = 16; fanin = 256; fanout = 256; }
  else if (i < OFF_W5) { src = a.W4; off = OFF_W4; ncts = 16; fanin = 256; fanout = 256; }
  else if (i < OFF_W6) { src = a.W5; off = OFF_W5; ncts = 16; fanin = 319; fanout = 256; shift = true; }
  else if (i < OFF_W7) { src = a.W6; off = OFF_W6; ncts = 16; fanin = 256; fanout = 256; }
  else if (i < OFF_WF) { src = a.W7; off = OFF_W7; ncts = 16; fanin = 256; fanout = 256; }
  else if (i < OFF_WV) { src = a.Wf; off = OFF_WF; ncts = 16; fanin = 256; fanout = 256; }
  else if (i < OFF_WA) { src = a.Wv; off = OFF_WV; ncts = 8;  fanin = 319; fanout = 128; }
  else if (i < OFF_WR) { src = a.Wa; off = OFF_WA; ncts = 1;  fanin = 256; fanout = 1; mode = 1; }
  else                 { src = a.Wr; off = OFF_WR; ncts = 1;  fanin = 128; fanout = 3; mode = 2; }

  const int idx  = i - off;
  const int j    = idx & 7;
  const int lane = (idx >> 3) & 63;
  const int rem  = idx >> 9;              // ct + ncts*ks
  const int ctg  = rem % ncts;
  const int ks   = rem / ncts;
  const int k    = ks * 32 + ((lane >> 4) << 3) + j;
  const int col  = ctg * 16 + (lane & 15);

  float v;
  if (mode == 1) {          // WA: 256x1
    v = (col == 0 && k < fanin) ? src[k] : 0.f;
  } else if (mode == 2) {   // WR: 128x3
    v = (col < 3 && k < fanin) ? src[(size_t)k * 3 + col] : 0.f;
  } else if (shift) {       // W5: k 0..62 = pts, k63 = 0 pad, k>=64 -> h rows k-1
    v = (k < 63) ? src[(size_t)k * 256 + col]
                 : ((k == 63) ? 0.f : src[(size_t)(k - 1) * 256 + col]);
  } else {
    v = (k < fanin) ? src[(size_t)k * fanout + col] : 0.f;
  }
  __bf16 bb = (__bf16)v;
  a.ws[i] = __builtin_bit_cast(unsigned short, bb);
}

// ---------------------------------------------------------------------------
struct MainArgs {
  const float* x;
  const unsigned short* ws;
  const float *b0, *b1, *b2, *b3, *b4, *b5, *b6, *b7;
  const float *bfc, *ba, *bv, *br;
  float* out;
};

__global__ __launch_bounds__(256, 3) void nerf_kernel(MainArgs A) {
  extern __shared__ unsigned short lds[];
  unsigned short* h     = lds;                 // [64][256] bf16, swizzled
  unsigned short* pts   = lds + 64 * 256;      // [64][64]
  unsigned short* views = pts + 64 * 64;       // [64][64]

  const int tid  = threadIdx.x;
  const int lane = tid & 63;
  const int wave = tid >> 6;             // 0..3
  const int l15 = lane & 15;
  const int lk8 = (lane >> 4) << 3;
  const int lk4 = (lane >> 4) << 2;
  const int cb  = wave * 64;             // wave's 64-col slice
  const int ctb = wave * 4;              // col-tile base (256-col layers)
  const int rowg0 = blockIdx.x * 64;
  const unsigned short* ws = A.ws;

  stage_inputs(A.x, pts, views, rowg0, tid);
  __syncthreads();

  f4 acc[4][4];

  // L0: pts -> h (K=64). h fresh: single barrier after store.
  init_acc<4>(acc, A.b0, cb, lk4);
  phase<4, 2, 16, 64>(acc, pts, ws + OFF_W0, 0, ctb, lane, l15, lk8);
  store_h<true, 4>(acc, h, cb, l15, lk4);
  __syncthreads();

  // L1..L4: h -> h in place (read-done barrier; store; write-done barrier)
  init_acc<4>(acc, A.b1, cb, lk4);
  phase<4, 8, 16, 256>(acc, h, ws + OFF_W1, 0, ctb, lane, l15, lk8);
  __syncthreads();
  store_h<true, 4>(acc, h, cb, l15, lk4);
  __syncthreads();

  init_acc<4>(acc, A.b2, cb, lk4);
  phase<4, 8, 16, 256>(acc, h, ws + OFF_W2, 0, ctb, lane, l15, lk8);
  __syncthreads();
  store_h<true, 4>(acc, h, cb, l15, lk4);
  __syncthreads();

  init_acc<4>(acc, A.b3, cb, lk4);
  phase<4, 8, 16, 256>(acc, h, ws + OFF_W3, 0, ctb, lane, l15, lk8);
  __syncthreads();
  store_h<true, 4>(acc, h, cb, l15, lk4);
  __syncthreads();

  init_acc<4>(acc, A.b4, cb, lk4);
  phase<4, 8, 16, 256>(acc, h, ws + OFF_W4, 0, ctb, lane, l15, lk8);
  __syncthreads();
  store_h<true, 4>(acc, h, cb, l15, lk4);
  __syncthreads();

  // L5 (skip): [pts | h] (ks 0..1 = pts (k63 pad), ks 2..9 = h), in place
  init_acc<4>(acc, A.b5, cb, lk4);
  phase<4, 2, 16, 64>(acc, pts, ws + OFF_W5, 0, ctb, lane, l15, lk8);
  phase<4, 8, 16, 256>(acc, h, ws + OFF_W5, 2, ctb, lane, l15, lk8);
  __syncthreads();
  store_h<true, 4>(acc, h, cb, l15, lk4);
  __syncthreads();

  // L6, L7
  init_acc<4>(acc, A.b6, cb, lk4);
  phase<4, 8, 16, 256>(acc, h, ws + OFF_W6, 0, ctb, lane, l15, lk8);
  __syncthreads();
  store_h<true, 4>(acc, h, cb, l15, lk4);
  __syncthreads();

  init_acc<4>(acc, A.b7, cb, lk4);
  phase<4, 8, 16, 256>(acc, h, ws + OFF_W7, 0, ctb, lane, l15, lk8);
  __syncthreads();
  store_h<true, 4>(acc, h, cb, l15, lk4);
  __syncthreads();

  // alpha = h_final @ Wa + ba  (wave 0, standalone; read-only on h, runs
  // concurrent with other waves' feature-phase reads).
  if (wave == 0) {
    f4 accA[4][1];
#pragma unroll
    for (int rt = 0; rt < 4; ++rt) accA[rt][0] = (f4){0.f, 0.f, 0.f, 0.f};
    phase<1, 8, 1, 256>(accA, h, ws + OFF_WA, 0, 0, lane, l15, lk8);
    if (lk4 == 0) {
      const float ba0 = A.ba[0];
#pragma unroll
      for (int rt = 0; rt < 4; ++rt)
        A.out[(size_t)(rowg0 + rt * 16 + l15) * 4 + 3] = accA[rt][0][0] + ba0;
    }
  }

  // feature = h @ Wf + bf (no relu), in place
  init_acc<4>(acc, A.bfc, cb, lk4);
  phase<4, 8, 16, 256>(acc, h, ws + OFF_WF, 0, ctb, lane, l15, lk8);
  __syncthreads();
  store_h<false, 4>(acc, h, cb, l15, lk4);
  __syncthreads();

  // hv = relu([feature | views] @ Wv + bv) -> h cols 0..127 (wave w: 32 cols)
  {
    f4 acc2[4][2];
    const int cb2 = wave * 32;
    init_acc<2>(acc2, A.bv, cb2, lk4);
    phase<2, 8, 8, 256>(acc2, h, ws + OFF_WV, 0, wave * 2, lane, l15, lk8);
    phase<2, 2, 8, 64>(acc2, views, ws + OFF_WV, 8, wave * 2, lane, l15, lk8);
    __syncthreads();
    store_h<true, 2>(acc2, h, cb2, l15, lk4);
  }
  __syncthreads();

  // rgb = hv @ Wr + br (wave 0; reads h cols 0..127; cols 0..2 real)
  if (wave == 0) {
    f4 accR[4][1];
#pragma unroll
    for (int rt = 0; rt < 4; ++rt) accR[rt][0] = (f4){0.f, 0.f, 0.f, 0.f};
    phase<1, 4, 1, 256>(accR, h, ws + OFF_WR, 0, 0, lane, l15, lk8);
    if (lk4 == 0) {
#pragma unroll
      for (int rt = 0; rt < 4; ++rt) {
        float* o = A.out + (size_t)(rowg0 + rt * 16 + l15) * 4;
#pragma unroll
        for (int j = 0; j < 3; ++j) o[j] = accR[rt][0][j] + A.br[j];
      }
    }
  }
}

// ---------------------------------------------------------------------------
extern "C" void kernel_launch(void* const* d_in, const int* in_sizes, int n_in,
                              void* d_out, int out_size, void* d_ws, size_t ws_size,
                              hipStream_t stream) {
  // d_in order: x, W0,b0, W1,b1, ..., W7,b7, Wf,bf, Wa,ba, Wv,bv, Wr,br
  RepackArgs ra;
  ra.W0 = (const float*)d_in[1];  ra.W1 = (const float*)d_in[3];
  ra.W2 = (const float*)d_in[5];  ra.W3 = (const float*)d_in[7];
  ra.W4 = (const float*)d_in[9];  ra.W5 = (const float*)d_in[11];
  ra.W6 = (const float*)d_in[13]; ra.W7 = (const float*)d_in[15];
  ra.Wf = (const float*)d_in[17]; ra.Wv = (const float*)d_in[21];
  ra.Wa = (const float*)d_in[19]; ra.Wr = (const float*)d_in[23];
  ra.ws = (unsigned short*)d_ws;
  repack_kernel<<<(WS_TOTAL + 255) / 256, 256, 0, stream>>>(ra);

  MainArgs ma;
  ma.x   = (const float*)d_in[0];
  ma.ws  = (const unsigned short*)d_ws;
  ma.b0  = (const float*)d_in[2];  ma.b1 = (const float*)d_in[4];
  ma.b2  = (const float*)d_in[6];  ma.b3 = (const float*)d_in[8];
  ma.b4  = (const float*)d_in[10]; ma.b5 = (const float*)d_in[12];
  ma.b6  = (const float*)d_in[14]; ma.b7 = (const float*)d_in[16];
  ma.bfc = (const float*)d_in[18];
  ma.ba  = (const float*)d_in[20];
  ma.bv  = (const float*)d_in[22];
  ma.br  = (const float*)d_in[24];
  ma.out = (float*)d_out;

  const int n    = in_sizes[0] / 126;   // 131072
  const int grid = n / 64;              // 2048 blocks (4 waves, 64 rows)

  // LDS: h(32K) + pts(8K) + views(8K) = 49152 B -> 3 blocks/CU
  hipFuncSetAttribute(reinterpret_cast<const void*>(nerf_kernel),
                      hipFuncAttributeMaxDynamicSharedMemorySize, 49152);
  nerf_kernel<<<grid, 256, 49152, stream>>>(ma);
}

// Round 16
// 166.009 us; speedup vs baseline: 1.5222x; 1.5222x over previous
//
#include <hip/hip_runtime.h>
#include <hip/hip_bf16.h>

// ---------------------------------------------------------------------------
// NeRF fused MLP, bf16 MFMA (16x16x32), fp32 accum, swapped operands (C^T).
// R16 = R14 (best, 167us) + (a) register double-buffered B-fragments (next
// kstep's 4 weight loads issued before current kstep's MFMAs -> ~2x L2
// requests in flight) + (b) per-wave kstep rotation (waves start at different
// K offsets -> desynchronized L2 streams / no barrier-exit burst).
// Cooperative block: 4 waves, 64 rows, ping-pong hA/hB, 1 barrier/layer.
// Wave: 64 rows x 64 cols, acc[4][4] = 64 AGPR (proven spill-free cap).
// Deep (row&31) swizzle; fragment-order weights (coalesced 1KB b-loads).
// __launch_bounds__(256,2): 128 AGPR / 128 VGPR split.
// ---------------------------------------------------------------------------

typedef __bf16 bfrag __attribute__((ext_vector_type(8)));   // 8 bf16 = 4 VGPR
typedef float  f4    __attribute__((ext_vector_type(4)));   // C/D frag
typedef unsigned short us4 __attribute__((ext_vector_type(4))); // 8B LDS store

// ws layout (bf16 element offsets). Each layer: ncts*nks*512 elems,
// fragment order: elem((ks*ncts + ct)*512 + lane*8 + j) =
//   W[k = ks*32 + (lane>>4)*8 + j][col = ct*16 + (lane&15)]
constexpr int OFF_W0 = 0;        // ncts16 nks2
constexpr int OFF_W1 = 16384;    // ncts16 nks8
constexpr int OFF_W2 = 81920;
constexpr int OFF_W3 = 147456;
constexpr int OFF_W4 = 212992;
constexpr int OFF_W5 = 278528;   // ncts16 nks10 (skip: k63 = 0 pad, k>=64 -> h)
constexpr int OFF_W6 = 360448;
constexpr int OFF_W7 = 425984;
constexpr int OFF_WF = 491520;   // ncts16 nks8
constexpr int OFF_WV = 557056;   // ncts8 nks10 ([feature|views], k319 pad)
constexpr int OFF_WA = 598016;   // ncts1 nks8 (col 0 = Wa, rest 0)
constexpr int OFF_WR = 602112;   // ncts1 nks4 (cols 0..2 = Wr, rest 0)
constexpr int WS_TOTAL = 604160; // bf16 elems (~1.2 MB)

__device__ __forceinline__ unsigned swz256(int row, int k) {
  // XOR element bits 3..7 with row&31 -> 16-row fragment reads hit 16
  // distinct 16B chunks (2-way = free per m136).
  return (unsigned)((row * 256 + k) ^ ((row & 31) << 3));
}
__device__ __forceinline__ unsigned swz64(int row, int k) {
  return (unsigned)((row * 64 + k) ^ ((row & 7) << 3));
}

// MFMA phase: 4 row-tiles (64 rows) x NCT col-tiles, K = NKS*32.
// src = LDS activations (stride SSTR, swizzled) -> B operand (swapped).
// Weights (fragment order) -> A operand. acc holds C^T: lane l15 = h-row,
// (lane>>4)*4+j = 4 consecutive output cols.
// B-frags double-buffered across ksteps; per-wave kstep rotation.
template<int NCT, int NKS, int NCTS, int SSTR>
__device__ __forceinline__ void phase(f4 (&acc)[4][NCT],
    const unsigned short* __restrict__ src,
    const unsigned short* __restrict__ wt, int ks0, int ctb,
    int wave, int lane, int l15, int lk8) {
  const int start = (wave * NKS) >> 2;   // stagger waves across ksteps
  // preload b for the first (rotated) kstep
  bfrag bc[NCT];
  {
    const int kse = start & (NKS - 1);
    const unsigned short* wk =
        wt + ((size_t)(ks0 + kse) * NCTS + ctb) * 512 + lane * 8;
#pragma unroll
    for (int u = 0; u < NCT; ++u)
      bc[u] = *(const bfrag*)(wk + (size_t)u * 512);
  }
#pragma unroll
  for (int ks = 0; ks < NKS; ++ks) {
    const int kse = (ks + start) & (NKS - 1);
    const int kl = kse * 32 + lk8;
    bfrag a[4];
#pragma unroll
    for (int rt = 0; rt < 4; ++rt) {
      const int row = rt * 16 + l15;
      const unsigned idx = (SSTR == 256) ? swz256(row, kl) : swz64(row, kl);
      a[rt] = *(const bfrag*)(src + idx);
    }
    bfrag bn[NCT];
    if (ks + 1 < NKS) {                  // issue NEXT kstep's b-loads now
      const int kse2 = (ks + 1 + start) & (NKS - 1);
      const unsigned short* wk =
          wt + ((size_t)(ks0 + kse2) * NCTS + ctb) * 512 + lane * 8;
#pragma unroll
      for (int u = 0; u < NCT; ++u)
        bn[u] = *(const bfrag*)(wk + (size_t)u * 512);
    }
#pragma unroll
    for (int u = 0; u < NCT; ++u)
#pragma unroll
      for (int rt = 0; rt < 4; ++rt)
        acc[rt][u] = __builtin_amdgcn_mfma_f32_16x16x32_bf16(bc[u], a[rt], acc[rt][u], 0, 0, 0);
    if (ks + 1 < NKS) {
#pragma unroll
      for (int u = 0; u < NCT; ++u) bc[u] = bn[u];
    }
  }
}

// bias init: lane covers cols cb + ct*16 + lk4 + (0..3) -> float4 load
template<int NCT>
__device__ __forceinline__ void init_acc(f4 (&acc)[4][NCT],
    const float* __restrict__ bias, int cb, int lk4) {
#pragma unroll
  for (int ct = 0; ct < NCT; ++ct) {
    const float4 bv = *(const float4*)(bias + cb + ct * 16 + lk4);
    f4 v = {bv.x, bv.y, bv.z, bv.w};
#pragma unroll
    for (int rt = 0; rt < 4; ++rt) acc[rt][ct] = v;
  }
}

// epilogue: lane writes h[row = rt*16+l15][cb + ct*16 + lk4 .. +3] as one b64
template<bool RELU, int NCT>
__device__ __forceinline__ void store_h(f4 (&acc)[4][NCT],
    unsigned short* __restrict__ h, int cb, int l15, int lk4) {
#pragma unroll
  for (int ct = 0; ct < NCT; ++ct) {
    const int col0 = cb + ct * 16 + lk4;
#pragma unroll
    for (int rt = 0; rt < 4; ++rt) {
      us4 packed;
#pragma unroll
      for (int j = 0; j < 4; ++j) {
        float v = acc[rt][ct][j];
        if (RELU) v = fmaxf(v, 0.f);
        __bf16 bb = (__bf16)v;
        packed[j] = __builtin_bit_cast(unsigned short, bb);
      }
      *(us4*)(h + swz256(rt * 16 + l15, col0)) = packed;
    }
  }
}

// stage x -> pts[64][64] (cols 0..62, pad 63) and views[64][64] (x cols 63..125)
__device__ __forceinline__ void stage_inputs(const float* __restrict__ x,
    unsigned short* pts, unsigned short* views, int rowg0, int tid) {
  const int row = tid >> 2, seg = tid & 3;
  const float* xr = x + (size_t)(rowg0 + row) * 126;
  bfrag v0, v1;
#pragma unroll
  for (int q = 0; q < 4; ++q) {          // pts, float2 (8B-aligned: even offs)
    const int c = seg * 16 + 2 * q;
    float2 t = *(const float2*)(xr + c);
    v0[2 * q]     = (c     < 63) ? (__bf16)t.x : (__bf16)0.f;
    v0[2 * q + 1] = (c + 1 < 63) ? (__bf16)t.y : (__bf16)0.f;
  }
#pragma unroll
  for (int q = 0; q < 4; ++q) {
    const int c = seg * 16 + 8 + 2 * q;
    float2 t = *(const float2*)(xr + c);   // max c=62 -> reads x[63], in-bounds
    v1[2 * q]     = (c     < 63) ? (__bf16)t.x : (__bf16)0.f;
    v1[2 * q + 1] = (c + 1 < 63) ? (__bf16)t.y : (__bf16)0.f;
  }
  *(bfrag*)(pts + swz64(row, seg * 16))     = v0;
  *(bfrag*)(pts + swz64(row, seg * 16 + 8)) = v1;
  bfrag w0, w1;
#pragma unroll
  for (int j = 0; j < 8; ++j) {          // views, scalar guarded (odd base)
    const int c = seg * 16 + j;
    w0[j] = (c < 63) ? (__bf16)xr[63 + c] : (__bf16)0.f;
  }
#pragma unroll
  for (int j = 0; j < 8; ++j) {
    const int c = seg * 16 + 8 + j;
    w1[j] = (c < 63) ? (__bf16)xr[63 + c] : (__bf16)0.f;
  }
  *(bfrag*)(views + swz64(row, seg * 16))     = w0;
  *(bfrag*)(views + swz64(row, seg * 16 + 8)) = w1;
}

// ---------------------------------------------------------------------------
struct RepackArgs {
  const float *W0, *W1, *W2, *W3, *W4, *W5, *W6, *W7, *Wf, *Wv, *Wa, *Wr;
  unsigned short* ws;
};

__global__ void repack_kernel(RepackArgs a) {
  const int i = blockIdx.x * 256 + threadIdx.x;
  if (i >= WS_TOTAL) return;

  const float* src; int off, ncts, fanin, fanout; bool shift = false;
  int mode = 0;  // 0 = dense, 1 = WA (col0 only), 2 = WR (cols 0..2)
  if      (i < OFF_W1) { src = a.W0; off = OFF_W0; ncts = 16; fanin = 63;  fanout = 256; }
  else if (i < OFF_W2) { src = a.W1; off = OFF_W1; ncts = 16; fanin = 256; fanout = 256; }
  else if (i < OFF_W3) { src = a.W2; off = OFF_W2; ncts = 16; fanin = 256; fanout = 256; }
  else if (i < OFF_W4) { src = a.W3; off = OFF_W3; ncts = 16; fanin = 256; fanout = 256; }
  else if (i < OFF_W5) { src = a.W4; off = OFF_W4; ncts = 16; fanin = 256; fanout = 256; }
  else if (i < OFF_W6) { src = a.W5; off = OFF_W5; ncts = 16; fanin = 319; fanout = 256; shift = true; }
  else if (i < OFF_W7) { src = a.W6; off = OFF_W6; ncts = 16; fanin = 256; fanout = 256; }
  else if (i < OFF_WF) { src = a.W7; off = OFF_W7; ncts = 16; fanin = 256; fanout = 256; }
  else if (i < OFF_WV) { src = a.Wf; off = OFF_WF; ncts = 16; fanin = 256; fanout = 256; }
  else if (i < OFF_WA) { src = a.Wv; off = OFF_WV; ncts = 8;  fanin = 319; fanout = 128; }
  else if (i < OFF_WR) { src = a.Wa; off = OFF_WA; ncts = 1;  fanin = 256; fanout = 1; mode = 1; }
  else                 { src = a.Wr; off = OFF_WR; ncts = 1;  fanin = 128; fanout = 3; mode = 2; }

  const int idx  = i - off;
  const int j    = idx & 7;
  const int lane = (idx >> 3) & 63;
  const int rem  = idx >> 9;              // ct + ncts*ks
  const int ctg  = rem % ncts;
  const int ks   = rem / ncts;
  const int k    = ks * 32 + ((lane >> 4) << 3) + j;
  const int col  = ctg * 16 + (lane & 15);

  float v;
  if (mode == 1) {          // WA: 256x1
    v = (col == 0 && k < fanin) ? src[k] : 0.f;
  } else if (mode == 2) {   // WR: 128x3
    v = (col < 3 && k < fanin) ? src[(size_t)k * 3 + col] : 0.f;
  } else if (shift) {       // W5: k 0..62 = pts, k63 = 0 pad, k>=64 -> h rows k-1
    v = (k < 63) ? src[(size_t)k * 256 + col]
                 : ((k == 63) ? 0.f : src[(size_t)(k - 1) * 256 + col]);
  } else {
    v = (k < fanin) ? src[(size_t)k * fanout + col] : 0.f;
  }
  __bf16 bb = (__bf16)v;
  a.ws[i] = __builtin_bit_cast(unsigned short, bb);
}

// ---------------------------------------------------------------------------
struct MainArgs {
  const float* x;
  const unsigned short* ws;
  const float *b0, *b1, *b2, *b3, *b4, *b5, *b6, *b7;
  const float *bfc, *ba, *bv, *br;
  float* out;
};

__global__ __launch_bounds__(256, 2) void nerf_kernel(MainArgs A) {
  extern __shared__ unsigned short lds[];
  unsigned short* hA    = lds;                 // [64][256] bf16, swizzled
  unsigned short* hB    = lds + 64 * 256;      // [64][256]
  unsigned short* pts   = lds + 2 * 64 * 256;  // [64][64]
  unsigned short* views = pts + 64 * 64;       // [64][64]

  const int tid  = threadIdx.x;
  const int lane = tid & 63;
  const int wave = tid >> 6;             // 0..3
  const int l15 = lane & 15;
  const int lk8 = (lane >> 4) << 3;
  const int lk4 = (lane >> 4) << 2;
  const int cb  = wave * 64;             // wave's 64-col slice
  const int ctb = wave * 4;              // col-tile base (256-col layers)
  const int rowg0 = blockIdx.x * 64;
  const unsigned short* ws = A.ws;

  stage_inputs(A.x, pts, views, rowg0, tid);
  __syncthreads();

  f4 acc[4][4];

  // L0: pts -> hA (K=64)
  init_acc<4>(acc, A.b0, cb, lk4);
  phase<4, 2, 16, 64>(acc, pts, ws + OFF_W0, 0, ctb, wave, lane, l15, lk8);
  store_h<true, 4>(acc, hA, cb, l15, lk4);
  __syncthreads();

  // L1: hA -> hB
  init_acc<4>(acc, A.b1, cb, lk4);
  phase<4, 8, 16, 256>(acc, hA, ws + OFF_W1, 0, ctb, wave, lane, l15, lk8);
  store_h<true, 4>(acc, hB, cb, l15, lk4);
  __syncthreads();

  // L2: hB -> hA
  init_acc<4>(acc, A.b2, cb, lk4);
  phase<4, 8, 16, 256>(acc, hB, ws + OFF_W2, 0, ctb, wave, lane, l15, lk8);
  store_h<true, 4>(acc, hA, cb, l15, lk4);
  __syncthreads();

  // L3: hA -> hB
  init_acc<4>(acc, A.b3, cb, lk4);
  phase<4, 8, 16, 256>(acc, hA, ws + OFF_W3, 0, ctb, wave, lane, l15, lk8);
  store_h<true, 4>(acc, hB, cb, l15, lk4);
  __syncthreads();

  // L4: hB -> hA
  init_acc<4>(acc, A.b4, cb, lk4);
  phase<4, 8, 16, 256>(acc, hB, ws + OFF_W4, 0, ctb, wave, lane, l15, lk8);
  store_h<true, 4>(acc, hA, cb, l15, lk4);
  __syncthreads();

  // L5 (skip): [pts | hA] -> hB (ks 0..1 = pts (k63 pad), ks 2..9 = hA)
  init_acc<4>(acc, A.b5, cb, lk4);
  phase<4, 2, 16, 64>(acc, pts, ws + OFF_W5, 0, ctb, wave, lane, l15, lk8);
  phase<4, 8, 16, 256>(acc, hA, ws + OFF_W5, 2, ctb, wave, lane, l15, lk8);
  store_h<true, 4>(acc, hB, cb, l15, lk4);
  __syncthreads();

  // L6: hB -> hA
  init_acc<4>(acc, A.b6, cb, lk4);
  phase<4, 8, 16, 256>(acc, hB, ws + OFF_W6, 0, ctb, wave, lane, l15, lk8);
  store_h<true, 4>(acc, hA, cb, l15, lk4);
  __syncthreads();

  // L7: hA -> hB   (h_final = hB)
  init_acc<4>(acc, A.b7, cb, lk4);
  phase<4, 8, 16, 256>(acc, hA, ws + OFF_W7, 0, ctb, wave, lane, l15, lk8);
  store_h<true, 4>(acc, hB, cb, l15, lk4);
  __syncthreads();

  // alpha = h_final @ Wa + ba  (wave 0, standalone; reads hB only).
  // C^T: lanes 0..15 (lk4==0) hold col 0 in acc[rt][0][0].
  if (wave == 0) {
    f4 accA[4][1];
#pragma unroll
    for (int rt = 0; rt < 4; ++rt) accA[rt][0] = (f4){0.f, 0.f, 0.f, 0.f};
    phase<1, 8, 1, 256>(accA, hB, ws + OFF_WA, 0, 0, 0, lane, l15, lk8);
    if (lk4 == 0) {
      const float ba0 = A.ba[0];
#pragma unroll
      for (int rt = 0; rt < 4; ++rt)
        A.out[(size_t)(rowg0 + rt * 16 + l15) * 4 + 3] = accA[rt][0][0] + ba0;
    }
  }

  // feature = h_final @ Wf + bf (no relu): hB -> hA
  init_acc<4>(acc, A.bfc, cb, lk4);
  phase<4, 8, 16, 256>(acc, hB, ws + OFF_WF, 0, ctb, wave, lane, l15, lk8);
  store_h<false, 4>(acc, hA, cb, l15, lk4);
  __syncthreads();

  // hv = relu([feature | views] @ Wv + bv): hA + views -> hB cols 0..127
  {
    f4 acc2[4][2];
    const int cb2 = wave * 32;
    init_acc<2>(acc2, A.bv, cb2, lk4);
    phase<2, 8, 8, 256>(acc2, hA, ws + OFF_WV, 0, wave * 2, wave, lane, l15, lk8);
    phase<2, 2, 8, 64>(acc2, views, ws + OFF_WV, 8, wave * 2, wave, lane, l15, lk8);
    store_h<true, 2>(acc2, hB, cb2, l15, lk4);
  }
  __syncthreads();

  // rgb = hv @ Wr + br (wave 0; reads hB; cols 0..2 real -> lanes 0..15, j<3)
  if (wave == 0) {
    f4 accR[4][1];
#pragma unroll
    for (int rt = 0; rt < 4; ++rt) accR[rt][0] = (f4){0.f, 0.f, 0.f, 0.f};
    phase<1, 4, 1, 256>(accR, hB, ws + OFF_WR, 0, 0, 0, lane, l15, lk8);
    if (lk4 == 0) {
#pragma unroll
      for (int rt = 0; rt < 4; ++rt) {
        float* o = A.out + (size_t)(rowg0 + rt * 16 + l15) * 4;
#pragma unroll
        for (int j = 0; j < 3; ++j) o[j] = accR[rt][0][j] + A.br[j];
      }
    }
  }
}

// ---------------------------------------------------------------------------
extern "C" void kernel_launch(void* const* d_in, const int* in_sizes, int n_in,
                              void* d_out, int out_size, void* d_ws, size_t ws_size,
                              hipStream_t stream) {
  // d_in order: x, W0,b0, W1,b1, ..., W7,b7, Wf,bf, Wa,ba, Wv,bv, Wr,br
  RepackArgs ra;
  ra.W0 = (const float*)d_in[1];  ra.W1 = (const float*)d_in[3];
  ra.W2 = (const float*)d_in[5];  ra.W3 = (const float*)d_in[7];
  ra.W4 = (const float*)d_in[9];  ra.W5 = (const float*)d_in[11];
  ra.W6 = (const float*)d_in[13]; ra.W7 = (const float*)d_in[15];
  ra.Wf = (const float*)d_in[17]; ra.Wv = (const float*)d_in[21];
  ra.Wa = (const float*)d_in[19]; ra.Wr = (const float*)d_in[23];
  ra.ws = (unsigned short*)d_ws;
  repack_kernel<<<(WS_TOTAL + 255) / 256, 256, 0, stream>>>(ra);

  MainArgs ma;
  ma.x   = (const float*)d_in[0];
  ma.ws  = (const unsigned short*)d_ws;
  ma.b0  = (const float*)d_in[2];  ma.b1 = (const float*)d_in[4];
  ma.b2  = (const float*)d_in[6];  ma.b3 = (const float*)d_in[8];
  ma.b4  = (const float*)d_in[10]; ma.b5 = (const float*)d_in[12];
  ma.b6  = (const float*)d_in[14]; ma.b7 = (const float*)d_in[16];
  ma.bfc = (const float*)d_in[18];
  ma.ba  = (const float*)d_in[20];
  ma.bv  = (const float*)d_in[22];
  ma.br  = (const float*)d_in[24];
  ma.out = (float*)d_out;

  const int n    = in_sizes[0] / 126;   // 131072
  const int grid = n / 64;              // 2048 blocks (4 waves, 64 rows)

  // LDS: hA(32K) + hB(32K) + pts(8K) + views(8K) = 81920 B -> 2 blocks/CU
  hipFuncSetAttribute(reinterpret_cast<const void*>(nerf_kernel),
                      hipFuncAttributeMaxDynamicSharedMemorySize, 81920);
  nerf_kernel<<<grid, 256, 81920, stream>>>(ma);
}